// Round 6
// baseline (916.394 us; speedup 1.0000x reference)
//
#include <hip/hip_runtime.h>
#include <hip/hip_bf16.h>
#include <stdint.h>

// GAT layer, N=8192, D_IN=512, D_OUT=64.
// MEASUREMENT ROUND: k1 body x16, k2 body x4 (idempotent reps) so BOTH dispatches exceed the
// ~160us top-5 bar and surface their own counters. Opaque z*rep pointer offsets + unroll 1
// prevent LICM/DCE of the repeated work. T_k1 = k1_dur/16, T_k2 = k2_dur/4;
// overhead = dur_us - 16*T_k1 - 4*T_k2. Logic identical to round 4.

constexpr int NN = 8192;
constexpr int DIN = 512;
constexpr int DOUT = 64;
constexpr int K1REP = 16;
constexpr int K2REP = 4;

typedef __attribute__((ext_vector_type(4))) float f32x4;
typedef __attribute__((ext_vector_type(8))) short short8;
typedef int int32x4 __attribute__((ext_vector_type(4)));

__device__ __forceinline__ unsigned short f2bf(float x) {
  union { float f; uint32_t u; } v; v.f = x;
  return (unsigned short)((v.u + 0x7fffu + ((v.u >> 16) & 1u)) >> 16);
}

// fragment-order byte offset for element (k-row c, col d); k-map shared by A and B:
// k = g*4 + (i&3) + 16*(i>>2), lane16 = g*16 + (d&15).
__device__ __forceinline__ int frag_byte(int c, int d) {
  int g = (c >> 2) & 3;
  int i = (c & 3) | (((c >> 4) & 1) << 2);
  return ((c >> 5) << 12) | ((d >> 4) << 10) | (((g << 4) | (d & 15)) << 4) | (i << 1);
}

__global__ __launch_bounds__(256) void k1_wh(
    const float* __restrict__ h, const float* __restrict__ W,
    const float* __restrict__ a, unsigned short* __restrict__ whb,
    float* __restrict__ wh1, float* __restrict__ wh2) {
  const int t = threadIdx.x, w = t >> 6, l = t & 63;
  const int r0 = blockIdx.x * 16 + w * 4;     // 4 rows per wave
  const int q = l >> 4, cg = l & 15;          // lane = (k-quarter, col-quad)
  const float* h0 = h + (size_t)r0 * DIN + q * 128;
  const float* Wp = W + (size_t)(q * 128) * DOUT + cg * 4;
  int z = 0;
  asm volatile("" : "+v"(z));   // opaque zero: defeats cross-rep LICM/DCE
#pragma unroll 1
  for (int rep = 0; rep < K1REP; ++rep) {
    const float* h0r = h0 + (size_t)(z * rep);
    const float* Wpr = Wp + (size_t)(z * rep);
    f32x4 acc[4] = {};
#pragma unroll 4
    for (int kk = 0; kk < 32; ++kk) {
      const float* wr = Wpr + (size_t)kk * 4 * DOUT;
      float4 w0 = *(const float4*)(wr);
      float4 w1 = *(const float4*)(wr + DOUT);
      float4 w2 = *(const float4*)(wr + 2 * DOUT);
      float4 w3 = *(const float4*)(wr + 3 * DOUT);
#pragma unroll
      for (int r = 0; r < 4; ++r) {
        float4 h4 = *(const float4*)(h0r + (size_t)r * DIN + kk * 4);
        acc[r][0] = fmaf(h4.x, w0.x, acc[r][0]); acc[r][1] = fmaf(h4.x, w0.y, acc[r][1]);
        acc[r][2] = fmaf(h4.x, w0.z, acc[r][2]); acc[r][3] = fmaf(h4.x, w0.w, acc[r][3]);
        acc[r][0] = fmaf(h4.y, w1.x, acc[r][0]); acc[r][1] = fmaf(h4.y, w1.y, acc[r][1]);
        acc[r][2] = fmaf(h4.y, w1.z, acc[r][2]); acc[r][3] = fmaf(h4.y, w1.w, acc[r][3]);
        acc[r][0] = fmaf(h4.z, w2.x, acc[r][0]); acc[r][1] = fmaf(h4.z, w2.y, acc[r][1]);
        acc[r][2] = fmaf(h4.z, w2.z, acc[r][2]); acc[r][3] = fmaf(h4.z, w2.w, acc[r][3]);
        acc[r][0] = fmaf(h4.w, w3.x, acc[r][0]); acc[r][1] = fmaf(h4.w, w3.y, acc[r][1]);
        acc[r][2] = fmaf(h4.w, w3.z, acc[r][2]); acc[r][3] = fmaf(h4.w, w3.w, acc[r][3]);
      }
    }
    // reduce over the 4 k-quarters
#pragma unroll
    for (int r = 0; r < 4; ++r)
#pragma unroll
      for (int cpt = 0; cpt < 4; ++cpt) {
        float v = acc[r][cpt];
        v += __shfl_xor(v, 16, 64);
        v += __shfl_xor(v, 32, 64);
        acc[r][cpt] = v;
      }
    float4 a1v = *(const float4*)(a + cg * 4);
    float4 a2v = *(const float4*)(a + DOUT + cg * 4);
#pragma unroll
    for (int r = 0; r < 4; ++r) {
      float d1 = acc[r][0] * a1v.x + acc[r][1] * a1v.y + acc[r][2] * a1v.z + acc[r][3] * a1v.w;
      float d2 = acc[r][0] * a2v.x + acc[r][1] * a2v.y + acc[r][2] * a2v.z + acc[r][3] * a2v.w;
#pragma unroll
      for (int m = 8; m >= 1; m >>= 1) { d1 += __shfl_xor(d1, m, 64); d2 += __shfl_xor(d2, m, 64); }
      if (l == 0) { wh1[r0 + r] = d1; wh2[r0 + r] = d2; }
      if (l < 16) {
        whb[frag_byte(r0 + r, cg * 4 + 0) >> 1] = f2bf(acc[r][0]);
        whb[frag_byte(r0 + r, cg * 4 + 1) >> 1] = f2bf(acc[r][1]);
        whb[frag_byte(r0 + r, cg * 4 + 2) >> 1] = f2bf(acc[r][2]);
        whb[frag_byte(r0 + r, cg * 4 + 3) >> 1] = f2bf(acc[r][3]);
      }
    }
  }
}

struct KRegs {
  int32x4 a0, a1;
  float4 f0, f1;
  uint4 v0, v1, v2, v3;
};

__global__ __launch_bounds__(512, 4) void k2_attn(
    const int* __restrict__ adj, const unsigned short* __restrict__ whb,
    const float* __restrict__ wh1, const float* __restrict__ wh2,
    float* __restrict__ out) {
  __shared__ float accs[8][16][64];
  __shared__ float lsum[8][16];
  const int t = threadIdx.x, w = t >> 6, l = t & 63;
  const int r0 = blockIdx.x * 16;
  const int row = l & 15, g = l >> 4;
  const float wh1r = wh1[r0 + row];
  const int jb = w * 1024 + 4 * g;  // wave-private 1024-j stripe; lane j-run base
  const int32x4* adjp0 = (const int32x4*)(adj + (size_t)(r0 + row) * NN + jb);
  const float4* w2p0 = (const float4*)(wh2 + jb);
  const uint4* vp0 = (const uint4*)whb + (size_t)w * 8192 + l;  // w*128KB stripe of whb
  int z = 0;
  asm volatile("" : "+v"(z));   // opaque zero

#define LOADC(R, c) do { \
    R.a0 = __builtin_nontemporal_load(adjp + (c) * 8); \
    R.a1 = __builtin_nontemporal_load(adjp + (c) * 8 + 4); \
    R.f0 = w2p[(c) * 8]; R.f1 = w2p[(c) * 8 + 4]; \
    R.v0 = vp[(c) * 256]; R.v1 = vp[(c) * 256 + 64]; \
    R.v2 = vp[(c) * 256 + 128]; R.v3 = vp[(c) * 256 + 192]; \
  } while (0)

#define SC(pv, av, fv) { float s_ = wh1r + (fv); s_ = fmaxf(s_, 0.2f * s_); \
                         float e_ = __expf(s_); pv = ((av) > 0) ? e_ : 0.f; }

#define PK2(lo, hi) ({ __hip_bfloat162 b_ = __float22bfloat162_rn(float2{(lo), (hi)}); \
                       *(uint32_t*)&b_; })

#define COMP(R) do { \
    float p0, p1, p2, p3, p4, p5, p6, p7; \
    SC(p0, R.a0.x, R.f0.x) SC(p1, R.a0.y, R.f0.y) SC(p2, R.a0.z, R.f0.z) SC(p3, R.a0.w, R.f0.w) \
    SC(p4, R.a1.x, R.f1.x) SC(p5, R.a1.y, R.f1.y) SC(p6, R.a1.z, R.f1.z) SC(p7, R.a1.w, R.f1.w) \
    lacc += ((p0 + p1) + (p2 + p3)) + ((p4 + p5) + (p6 + p7)); \
    union { uint32_t u[4]; short8 s; } af; \
    af.u[0] = PK2(p0, p1); af.u[1] = PK2(p2, p3); \
    af.u[2] = PK2(p4, p5); af.u[3] = PK2(p6, p7); \
    union { uint4 q; short8 s; } b0, b1, b2, b3; \
    b0.q = R.v0; b1.q = R.v1; b2.q = R.v2; b3.q = R.v3; \
    acc0 = __builtin_amdgcn_mfma_f32_16x16x32_bf16(af.s, b0.s, acc0, 0, 0, 0); \
    acc1 = __builtin_amdgcn_mfma_f32_16x16x32_bf16(af.s, b1.s, acc1, 0, 0, 0); \
    acc2 = __builtin_amdgcn_mfma_f32_16x16x32_bf16(af.s, b2.s, acc2, 0, 0, 0); \
    acc3 = __builtin_amdgcn_mfma_f32_16x16x32_bf16(af.s, b3.s, acc3, 0, 0, 0); \
  } while (0)

#pragma unroll 1
  for (int rep = 0; rep < K2REP; ++rep) {
    const int32x4* adjp = adjp0 + (size_t)(z * rep);
    const float4* w2p = w2p0 + (size_t)(z * rep);
    const uint4* vp = vp0 + (size_t)(z * rep);
    f32x4 acc0 = {}, acc1 = {}, acc2 = {}, acc3 = {};
    float lacc = 0.f;
    KRegs A, B;
    LOADC(A, 0);
    LOADC(B, 1);
    for (int c = 0; c + 2 < 32; c += 2) {
      COMP(A); LOADC(A, c + 2);
      COMP(B); LOADC(B, c + 3);
    }
    COMP(A);
    COMP(B);

    // denominator: reduce over the 4 j-run groups within the wave
    lacc += __shfl_xor(lacc, 16, 64);
    lacc += __shfl_xor(lacc, 32, 64);
    if (l < 16) lsum[w][l] = lacc;
    // stash acc; C/D layout: row = (lane>>4)*4 + reg, col = n*16 + (lane&15)
    {
      const int rb = (l >> 4) * 4, cl = l & 15;
#define WACC(an, n) { accs[w][rb + 0][(n)*16 + cl] = an[0]; accs[w][rb + 1][(n)*16 + cl] = an[1]; \
                      accs[w][rb + 2][(n)*16 + cl] = an[2]; accs[w][rb + 3][(n)*16 + cl] = an[3]; }
      WACC(acc0, 0) WACC(acc1, 1) WACC(acc2, 2) WACC(acc3, 3)
#undef WACC
    }
    __syncthreads();
    // sum the 8 wave-stripes, normalize, elu, store
    if (t < 256) {
      const int rr = t >> 4, dq = (t & 15) * 4;
      float sx = 0.f, sy = 0.f, sz = 0.f, sw = 0.f, L = 0.f;
#pragma unroll
      for (int ws = 0; ws < 8; ++ws) {
        float4 sv = *(const float4*)&accs[ws][rr][dq];
        sx += sv.x; sy += sv.y; sz += sv.z; sw += sv.w;
        L += lsum[ws][rr];
      }
      float inv = 1.0f / L;
      float4 o;
      float v;
      v = sx * inv; o.x = v > 0.f ? v : __expf(v) - 1.f;
      v = sy * inv; o.y = v > 0.f ? v : __expf(v) - 1.f;
      v = sz * inv; o.z = v > 0.f ? v : __expf(v) - 1.f;
      v = sw * inv; o.w = v > 0.f ? v : __expf(v) - 1.f;
      *(float4*)(out + (size_t)(r0 + rr) * DOUT + dq) = o;
    }
    __syncthreads();  // protect accs/lsum before next rep overwrites
  }
#undef LOADC
#undef SC
#undef PK2
#undef COMP
}

extern "C" void kernel_launch(void* const* d_in, const int* in_sizes, int n_in,
                              void* d_out, int out_size, void* d_ws, size_t ws_size,
                              hipStream_t stream) {
  const float* h = (const float*)d_in[0];
  const float* W = (const float*)d_in[1];
  const float* a = (const float*)d_in[2];
  const int* adj = (const int*)d_in[3];
  float* out = (float*)d_out;
  char* ws = (char*)d_ws;
  unsigned short* whb = (unsigned short*)ws;            // 1 MB bf16 Wh, fragment order
  float* wh1 = (float*)(ws + (1 << 20));                // 32 KB
  float* wh2 = (float*)(ws + (1 << 20) + (32 << 10));   // 32 KB
  k1_wh<<<NN / 16, 256, 0, stream>>>(h, W, a, whb, wh1, wh2);
  k2_attn<<<NN / 16, 512, 0, stream>>>(adj, whb, wh1, wh2, out);
}

// Round 11
// 698.790 us; speedup vs baseline: 1.3114x; 1.3114x over previous
//
#include <hip/hip_runtime.h>
#include <hip/hip_bf16.h>
#include <stdint.h>

// GAT layer, N=8192, D_IN=512, D_OUT=64.
// k1: Wh = h@W (f32), 4 rows/wave; stores Wh bf16 in MFMA-fragment order + wh1/wh2 (f32).
// k2: one block = 16 rows x all 8192 j, 8 waves x 1024-j stripes. LATENCY FIX (r6 PMC:
//     hbm 19.6%, VALU 24.6%, Mfma 3.8% => latency-bound, ~1 chunk in flight/wave):
//     adj (HBM) prefetched 4-deep, wh2/whb (L2-hot) 2-deep, 32-chunk body fully unrolled.
// MEASUREMENT: k2 body x4 (idempotent, anti-LICM opaque offsets) for A/B vs r6's 365us
// dispatch. T_k2' = dispatch/4 (warm-rep caveat: L3 absorbs ~half of adj re-reads).
// Next round strips the x4 once counters confirm/refute the prefetch mechanism.

constexpr int NN = 8192;
constexpr int DIN = 512;
constexpr int DOUT = 64;
constexpr int K2REP = 4;

typedef __attribute__((ext_vector_type(4))) float f32x4;
typedef __attribute__((ext_vector_type(8))) short short8;
typedef int int32x4 __attribute__((ext_vector_type(4)));

__device__ __forceinline__ unsigned short f2bf(float x) {
  union { float f; uint32_t u; } v; v.f = x;
  return (unsigned short)((v.u + 0x7fffu + ((v.u >> 16) & 1u)) >> 16);
}

// fragment-order byte offset for element (k-row c, col d); k-map shared by A and B:
// k = g*4 + (i&3) + 16*(i>>2), lane16 = g*16 + (d&15).
__device__ __forceinline__ int frag_byte(int c, int d) {
  int g = (c >> 2) & 3;
  int i = (c & 3) | (((c >> 4) & 1) << 2);
  return ((c >> 5) << 12) | ((d >> 4) << 10) | (((g << 4) | (d & 15)) << 4) | (i << 1);
}

__global__ __launch_bounds__(256) void k1_wh(
    const float* __restrict__ h, const float* __restrict__ W,
    const float* __restrict__ a, unsigned short* __restrict__ whb,
    float* __restrict__ wh1, float* __restrict__ wh2) {
  const int t = threadIdx.x, w = t >> 6, l = t & 63;
  const int r0 = blockIdx.x * 16 + w * 4;     // 4 rows per wave
  const int q = l >> 4, cg = l & 15;          // lane = (k-quarter, col-quad)
  const float* h0 = h + (size_t)r0 * DIN + q * 128;
  const float* Wp = W + (size_t)(q * 128) * DOUT + cg * 4;
  f32x4 acc[4] = {};
#pragma unroll 4
  for (int kk = 0; kk < 32; ++kk) {
    const float* wr = Wp + (size_t)kk * 4 * DOUT;
    float4 w0 = *(const float4*)(wr);
    float4 w1 = *(const float4*)(wr + DOUT);
    float4 w2 = *(const float4*)(wr + 2 * DOUT);
    float4 w3 = *(const float4*)(wr + 3 * DOUT);
#pragma unroll
    for (int r = 0; r < 4; ++r) {
      float4 h4 = *(const float4*)(h0 + (size_t)r * DIN + kk * 4);
      acc[r][0] = fmaf(h4.x, w0.x, acc[r][0]); acc[r][1] = fmaf(h4.x, w0.y, acc[r][1]);
      acc[r][2] = fmaf(h4.x, w0.z, acc[r][2]); acc[r][3] = fmaf(h4.x, w0.w, acc[r][3]);
      acc[r][0] = fmaf(h4.y, w1.x, acc[r][0]); acc[r][1] = fmaf(h4.y, w1.y, acc[r][1]);
      acc[r][2] = fmaf(h4.y, w1.z, acc[r][2]); acc[r][3] = fmaf(h4.y, w1.w, acc[r][3]);
      acc[r][0] = fmaf(h4.z, w2.x, acc[r][0]); acc[r][1] = fmaf(h4.z, w2.y, acc[r][1]);
      acc[r][2] = fmaf(h4.z, w2.z, acc[r][2]); acc[r][3] = fmaf(h4.z, w2.w, acc[r][3]);
      acc[r][0] = fmaf(h4.w, w3.x, acc[r][0]); acc[r][1] = fmaf(h4.w, w3.y, acc[r][1]);
      acc[r][2] = fmaf(h4.w, w3.z, acc[r][2]); acc[r][3] = fmaf(h4.w, w3.w, acc[r][3]);
    }
  }
  // reduce over the 4 k-quarters
#pragma unroll
  for (int r = 0; r < 4; ++r)
#pragma unroll
    for (int cpt = 0; cpt < 4; ++cpt) {
      float v = acc[r][cpt];
      v += __shfl_xor(v, 16, 64);
      v += __shfl_xor(v, 32, 64);
      acc[r][cpt] = v;
    }
  float4 a1v = *(const float4*)(a + cg * 4);
  float4 a2v = *(const float4*)(a + DOUT + cg * 4);
#pragma unroll
  for (int r = 0; r < 4; ++r) {
    float d1 = acc[r][0] * a1v.x + acc[r][1] * a1v.y + acc[r][2] * a1v.z + acc[r][3] * a1v.w;
    float d2 = acc[r][0] * a2v.x + acc[r][1] * a2v.y + acc[r][2] * a2v.z + acc[r][3] * a2v.w;
#pragma unroll
    for (int m = 8; m >= 1; m >>= 1) { d1 += __shfl_xor(d1, m, 64); d2 += __shfl_xor(d2, m, 64); }
    if (l == 0) { wh1[r0 + r] = d1; wh2[r0 + r] = d2; }
    if (l < 16) {
      whb[frag_byte(r0 + r, cg * 4 + 0) >> 1] = f2bf(acc[r][0]);
      whb[frag_byte(r0 + r, cg * 4 + 1) >> 1] = f2bf(acc[r][1]);
      whb[frag_byte(r0 + r, cg * 4 + 2) >> 1] = f2bf(acc[r][2]);
      whb[frag_byte(r0 + r, cg * 4 + 3) >> 1] = f2bf(acc[r][3]);
    }
  }
}

struct KAdj { int32x4 a0, a1; };                 // 8 VGPR/stage, 4 stages
struct KWv  { float4 f0, f1; uint4 v0, v1, v2, v3; };  // 24 VGPR/stage, 2 stages

// (512,3): VGPR cap ~170 avoids forced spill; actual ~130 still gives 4 waves/SIMD.
__global__ __launch_bounds__(512, 3) void k2_attn(
    const int* __restrict__ adj, const unsigned short* __restrict__ whb,
    const float* __restrict__ wh1, const float* __restrict__ wh2,
    float* __restrict__ out) {
  __shared__ float accs[8][16][64];
  __shared__ float lsum[8][16];
  const int t = threadIdx.x, w = t >> 6, l = t & 63;
  const int r0 = blockIdx.x * 16;
  const int row = l & 15, g = l >> 4;
  const float wh1r = wh1[r0 + row];
  const int jb = w * 1024 + 4 * g;  // wave-private 1024-j stripe; lane j-run base
  const int32x4* adjp0 = (const int32x4*)(adj + (size_t)(r0 + row) * NN + jb);
  const float4* w2p0 = (const float4*)(wh2 + jb);
  const uint4* vp0 = (const uint4*)whb + (size_t)w * 8192 + l;  // w*128KB stripe of whb
  int z = 0;
  asm volatile("" : "+v"(z));   // opaque zero: defeats cross-rep LICM/DCE

#define ADJLOAD(P, c) do { \
    P.a0 = __builtin_nontemporal_load(adjp + (c) * 8); \
    P.a1 = __builtin_nontemporal_load(adjp + (c) * 8 + 4); \
  } while (0)

#define WVLOAD(X, c) do { \
    X.f0 = w2p[(c) * 8]; X.f1 = w2p[(c) * 8 + 4]; \
    X.v0 = vp[(c) * 256]; X.v1 = vp[(c) * 256 + 64]; \
    X.v2 = vp[(c) * 256 + 128]; X.v3 = vp[(c) * 256 + 192]; \
  } while (0)

#define SC(pv, av, fv) { float s_ = wh1r + (fv); s_ = fmaxf(s_, 0.2f * s_); \
                         float e_ = __expf(s_); pv = ((av) > 0) ? e_ : 0.f; }

#define PK2(lo, hi) ({ __hip_bfloat162 b_ = __float22bfloat162_rn(float2{(lo), (hi)}); \
                       *(uint32_t*)&b_; })

#define COMP(P, X) do { \
    float p0, p1, p2, p3, p4, p5, p6, p7; \
    SC(p0, P.a0.x, X.f0.x) SC(p1, P.a0.y, X.f0.y) SC(p2, P.a0.z, X.f0.z) SC(p3, P.a0.w, X.f0.w) \
    SC(p4, P.a1.x, X.f1.x) SC(p5, P.a1.y, X.f1.y) SC(p6, P.a1.z, X.f1.z) SC(p7, P.a1.w, X.f1.w) \
    lacc += ((p0 + p1) + (p2 + p3)) + ((p4 + p5) + (p6 + p7)); \
    union { uint32_t u[4]; short8 s; } af; \
    af.u[0] = PK2(p0, p1); af.u[1] = PK2(p2, p3); \
    af.u[2] = PK2(p4, p5); af.u[3] = PK2(p6, p7); \
    union { uint4 q; short8 s; } b0, b1, b2, b3; \
    b0.q = X.v0; b1.q = X.v1; b2.q = X.v2; b3.q = X.v3; \
    acc0 = __builtin_amdgcn_mfma_f32_16x16x32_bf16(af.s, b0.s, acc0, 0, 0, 0); \
    acc1 = __builtin_amdgcn_mfma_f32_16x16x32_bf16(af.s, b1.s, acc1, 0, 0, 0); \
    acc2 = __builtin_amdgcn_mfma_f32_16x16x32_bf16(af.s, b2.s, acc2, 0, 0, 0); \
    acc3 = __builtin_amdgcn_mfma_f32_16x16x32_bf16(af.s, b3.s, acc3, 0, 0, 0); \
  } while (0)

// STEP(chunk c): issue adj for c+3 (4-deep) and wh2/whb for c+1 (2-deep), then compute c.
// Clamped tail issues re-read chunk 31 (in-bounds, idempotent, negligible).
#define STEP(Puse, Xuse, Pfill, Xfill, c) do { \
    ADJLOAD(Pfill, ((c) + 3 <= 31) ? (c) + 3 : 31); \
    WVLOAD(Xfill, ((c) + 1 <= 31) ? (c) + 1 : 31); \
    COMP(Puse, Xuse); \
  } while (0)

#define QUAD(q) \
    STEP(P0, X0, P3, X1, 4 * (q) + 0); \
    STEP(P1, X1, P0, X0, 4 * (q) + 1); \
    STEP(P2, X0, P1, X1, 4 * (q) + 2); \
    STEP(P3, X1, P2, X0, 4 * (q) + 3);

#pragma unroll 1
  for (int rep = 0; rep < K2REP; ++rep) {
    const int32x4* adjp = adjp0 + (size_t)(z * rep);
    const float4* w2p = w2p0 + (size_t)(z * rep);
    const uint4* vp = vp0 + (size_t)(z * rep);
    f32x4 acc0 = {}, acc1 = {}, acc2 = {}, acc3 = {};
    float lacc = 0.f;
    KAdj P0, P1, P2, P3;
    KWv X0, X1;
    ADJLOAD(P0, 0); ADJLOAD(P1, 1); ADJLOAD(P2, 2);
    WVLOAD(X0, 0);
    QUAD(0) QUAD(1) QUAD(2) QUAD(3) QUAD(4) QUAD(5) QUAD(6) QUAD(7)

    // denominator: reduce over the 4 j-run groups within the wave
    lacc += __shfl_xor(lacc, 16, 64);
    lacc += __shfl_xor(lacc, 32, 64);
    if (l < 16) lsum[w][l] = lacc;
    // stash acc; C/D layout: row = (lane>>4)*4 + reg, col = n*16 + (lane&15)
    {
      const int rb = (l >> 4) * 4, cl = l & 15;
#define WACC(an, n) { accs[w][rb + 0][(n)*16 + cl] = an[0]; accs[w][rb + 1][(n)*16 + cl] = an[1]; \
                      accs[w][rb + 2][(n)*16 + cl] = an[2]; accs[w][rb + 3][(n)*16 + cl] = an[3]; }
      WACC(acc0, 0) WACC(acc1, 1) WACC(acc2, 2) WACC(acc3, 3)
#undef WACC
    }
    __syncthreads();
    // sum the 8 wave-stripes, normalize, elu, store
    if (t < 256) {
      const int rr = t >> 4, dq = (t & 15) * 4;
      float sx = 0.f, sy = 0.f, sz = 0.f, sw = 0.f, L = 0.f;
#pragma unroll
      for (int ws = 0; ws < 8; ++ws) {
        float4 sv = *(const float4*)&accs[ws][rr][dq];
        sx += sv.x; sy += sv.y; sz += sv.z; sw += sv.w;
        L += lsum[ws][rr];
      }
      float inv = 1.0f / L;
      float4 o;
      float v;
      v = sx * inv; o.x = v > 0.f ? v : __expf(v) - 1.f;
      v = sy * inv; o.y = v > 0.f ? v : __expf(v) - 1.f;
      v = sz * inv; o.z = v > 0.f ? v : __expf(v) - 1.f;
      v = sw * inv; o.w = v > 0.f ? v : __expf(v) - 1.f;
      *(float4*)(out + (size_t)(r0 + rr) * DOUT + dq) = o;
    }
    __syncthreads();  // protect accs/lsum before next rep overwrites
  }
#undef ADJLOAD
#undef WVLOAD
#undef SC
#undef PK2
#undef COMP
#undef STEP
#undef QUAD
}

extern "C" void kernel_launch(void* const* d_in, const int* in_sizes, int n_in,
                              void* d_out, int out_size, void* d_ws, size_t ws_size,
                              hipStream_t stream) {
  const float* h = (const float*)d_in[0];
  const float* W = (const float*)d_in[1];
  const float* a = (const float*)d_in[2];
  const int* adj = (const int*)d_in[3];
  float* out = (float*)d_out;
  char* ws = (char*)d_ws;
  unsigned short* whb = (unsigned short*)ws;            // 1 MB bf16 Wh, fragment order
  float* wh1 = (float*)(ws + (1 << 20));                // 32 KB
  float* wh2 = (float*)(ws + (1 << 20) + (32 << 10));   // 32 KB
  k1_wh<<<NN / 16, 256, 0, stream>>>(h, W, a, whb, wh1, wh2);
  k2_attn<<<NN / 16, 512, 0, stream>>>(adj, whb, wh1, wh2, out);
}